// Round 14
// baseline (670.777 us; speedup 1.0000x reference)
//
#include <hip/hip_runtime.h>
#include <hip/hip_bf16.h>
#include <cstdint>
#include <cstddef>

// QRNN encoder, 3 layers. T=512 B=64 E=300 H=800.
// Chunked (4 x 128 steps, b-major rows b*128+t per chunk) fused GEMM+scan
// kernels packed into a 3-role pipeline per dispatch:
//   D(c) = { L1(c), L2(c-1), L0(c+1) } with double-buffered H0/H1.
// R14: A-operand loaded DIRECT to registers (global_load_dwordx4 per
// fragment, issued pre-barrier) — cuts ~40% of LDS traffic (stage+read
// round-trip); B stays LDS-staged (shared across m-frags/waves).
// Role bodies:
//   scan_h: 128x192 zfo-GEMM tile (z at 2hl, f at 2hl+1, o at 128+hl)
//     + in-LDS segment scan (affine coeffs in registers) + h=sigmoid(o')*c.
//   scan_c: zf-only 128x128 tile + scan, carry/out only.
// GEMM: BK=64, XOR-swizzled B staging (0 bank conflicts), XCD-aware block
// swizzle, async global_load_lds for B. Workspace ~85 MB.

typedef __bf16 bf16_t;
typedef __bf16 bf16x8 __attribute__((ext_vector_type(8)));
typedef float f32x4 __attribute__((ext_vector_type(4)));

#define T_C 128
#define NCHUNK 4
#define BATCH 64
#define EMB 300
#define HID 800
#define LDH 832                 // h buffer leading dim (K-pad for BK=64)
#define MC (T_C * BATCH)        // 8192 rows per chunk

__device__ __forceinline__ float fast_sigmoid(float x) {
  return 1.0f / (1.0f + __expf(-x));
}
__device__ __forceinline__ float fast_tanh(float x) {
  return 2.0f / (1.0f + __expf(-2.0f * x)) - 1.0f;
}
__device__ __forceinline__ float b2f(uint32_t u) {
  union { uint32_t i; float f; } x;
  x.i = u << 16;
  return x.f;
}

// ---- prep: sent [rows t*64+b][300] fp32 -> A0 bf16 b-major chunks:
// dst row = c*8192 + b*128 + t, cols 0..319 (zero K-pad). ----
__global__ __launch_bounds__(256) void cast_reorder_a0(
    const float* __restrict__ X, bf16_t* __restrict__ Y) {
  int idx = blockIdx.x * 256 + threadIdx.x;
  if (idx >= 32768 * 320) return;
  int r = idx / 320, col = idx - r * 320;
  const int cc = r >> 13, b = (r >> 7) & 63, t = r & 127;
  const int src = (cc * 128 + t) * 64 + b;
  float v = (col < EMB) ? X[(size_t)src * EMB + col] : 0.0f;
  Y[idx] = (bf16_t)v;
}

// ---- prep: weights -> transposed bf16 buffers.
// Merged zfo (z=0,1): Wm[2496][Kpad]; row n: tile j=n/192, r=n%192;
//   r<128: h=64j+(r>>1), src=(r&1)*800+h; r>=128: h=64j+(r-128), src=1600+h.
// zf-only (z=2): Wzf[1664][Kpad]; row n: h=n>>1, src=(n&1)*800+h. ----
__global__ __launch_bounds__(256) void transpose_cast_w(
    const float* __restrict__ W0, const float* __restrict__ W1,
    const float* __restrict__ W2, bf16_t* __restrict__ M0,
    bf16_t* __restrict__ M1, bf16_t* __restrict__ Z2) {
  const int z = blockIdx.z;
  const float* W = z == 0 ? W0 : (z == 1 ? W1 : W2);
  bf16_t* Wt = z == 0 ? M0 : (z == 1 ? M1 : Z2);
  const int K = z == 0 ? 300 : 800;
  const int Kpad = z == 0 ? 320 : 832;
  const int Npad = (z < 2) ? 2496 : 1664;
  const int i = blockIdx.x, j = blockIdx.y;
  if (i * 32 >= Npad || j * 32 >= Kpad) return;
  __shared__ float tile[32][33];
  const int tx = threadIdx.x & 31, ty = threadIdx.x >> 5;
#pragma unroll
  for (int r = 0; r < 32; r += 8) {
    const int k = j * 32 + ty + r;
    const int n = i * 32 + tx;
    int h, src;
    if (z < 2) {
      const int jt = n / 192, rr = n - jt * 192;
      if (rr < 128) {
        h = jt * 64 + (rr >> 1);
        src = (rr & 1) * 800 + h;
      } else {
        h = jt * 64 + (rr - 128);
        src = 1600 + h;
      }
    } else {
      h = n >> 1;
      src = (n & 1) * 800 + h;
    }
    const bool valid = (k < K) && (h < 800);
    tile[ty + r][tx] = valid ? W[(size_t)k * 2400 + src] : 0.0f;
  }
  __syncthreads();
#pragma unroll
  for (int r = 0; r < 32; r += 8) {
    const int n = i * 32 + ty + r, k = j * 32 + tx;
    if (n < Npad && k < Kpad)
      Wt[(size_t)n * Kpad + k] = (bf16_t)tile[tx][ty + r];
  }
}

// ---- async 16B global->LDS (wave-uniform base + lane*16 layout) ----
__device__ __forceinline__ void stage16(const bf16_t* gp, bf16_t* lp) {
  __builtin_amdgcn_global_load_lds((__attribute__((address_space(1))) void*)gp,
                                   (__attribute__((address_space(3))) void*)lp,
                                   16, 0, 0);
}

// GEMM core: 128 x (32*NTF) tile of A@Wt^T into Et[128][ETS] (bf16).
// 2x2 waves; each wave = 64 rows x (16*NTF) cols. A fragments loaded
// direct to registers (pre-barrier, coalesced dwordx4); B XOR-swizzle
// staged in LDS, conflict-free ds_read_b128 fragment reads.
template <int NTF, int ETS>
__device__ __forceinline__ void gemm_tile_to_lds(
    const bf16_t* __restrict__ A, const bf16_t* __restrict__ Bt,
    bf16_t* __restrict__ S, int K, int mBase, int nBase) {
  bf16_t* Bs = S;
  const int tid = threadIdx.x;
  const int wave = tid >> 6, lane = tid & 63;
  const int wm = wave >> 1, wn = wave & 1;
  const int srow = tid >> 3;
  const int scolSw = ((tid & 7) ^ (srow & 7)) * 8;
  const size_t bBase = (size_t)(nBase + srow) * K + scolSw;
  const int ldsOff = tid * 8;

  f32x4 acc[4][NTF];
#pragma unroll
  for (int mt = 0; mt < 4; ++mt)
#pragma unroll
    for (int nt = 0; nt < NTF; ++nt) {
      f32x4 zz = {0.0f, 0.0f, 0.0f, 0.0f};
      acc[mt][nt] = zz;
    }

  const int fr = lane & 15, fq = lane >> 4;
  const int x0 = fr & 7;
  const int ckEl0 = (fq ^ x0) * 8;
  const int ckEl1 = ((4 + fq) ^ x0) * 8;

  // A direct: row = mBase + wm*64 + mt*16 + fr, cols k0 + kh*32 + fq*8.
  const bf16_t* aP = A + (size_t)(mBase + wm * 64 + fr) * K + fq * 8;

  for (int k0 = 0; k0 < K; k0 += 64) {
#pragma unroll
    for (int p = 0; p < NTF; ++p)
      stage16(Bt + bBase + (size_t)(32 * p) * K + k0, &Bs[ldsOff + p * 2048]);
    bf16x8 afr[4][2];
#pragma unroll
    for (int mt = 0; mt < 4; ++mt)
#pragma unroll
      for (int kh = 0; kh < 2; ++kh)
        afr[mt][kh] =
            *(const bf16x8*)(aP + (size_t)(mt * 16) * K + k0 + kh * 32);
    __syncthreads();
#pragma unroll
    for (int kh = 0; kh < 2; ++kh) {
      const int ck = kh ? ckEl1 : ckEl0;
      bf16x8 bfv[NTF];
#pragma unroll
      for (int nt = 0; nt < NTF; ++nt)
        bfv[nt] = *(const bf16x8*)&Bs[(wn * (16 * NTF) + nt * 16 + fr) * 64 + ck];
#pragma unroll
      for (int mt = 0; mt < 4; ++mt)
#pragma unroll
        for (int nt = 0; nt < NTF; ++nt)
          acc[mt][nt] = __builtin_amdgcn_mfma_f32_16x16x32_bf16(
              afr[mt][kh], bfv[nt], acc[mt][nt], 0, 0, 0);
    }
    __syncthreads();
  }
  // C/D layout col=lane&15, row=(lane>>4)*4+r -> Et[row][col], stride ETS.
  bf16_t* Et = S;
#pragma unroll
  for (int mt = 0; mt < 4; ++mt)
#pragma unroll
    for (int nt = 0; nt < NTF; ++nt)
#pragma unroll
      for (int r = 0; r < 4; ++r)
        Et[(wm * 64 + mt * 16 + fq * 4 + r) * ETS + wn * (16 * NTF) + nt * 16 +
           fr] = (bf16_t)acc[mt][nt][r];
  __syncthreads();
}

// ---- role body: zfo-GEMM (192 cols) + fused scan + h epilogue ----
__device__ __forceinline__ void scan_h_body(
    const bf16_t* __restrict__ A, const bf16_t* __restrict__ Wm,
    const float* __restrict__ bias, bf16_t* __restrict__ Hout,
    float* __restrict__ carry, float* __restrict__ outC, int K, int outOff,
    int first, int last, int b, int ntile, bf16_t* S, float (*SA)[64],
    float (*SB)[64], float (*SC)[64]) {
  gemm_tile_to_lds<6, 196>(A, Wm, S, K, b * 128, ntile * 192);

  const uint32_t* Ep = (const uint32_t*)S;  // dword idx t*98+hl = (z,f)
  const int tid = threadIdx.x;
  const int hl = tid & 63, s = tid >> 6;
  const int h = ntile * 64 + hl;
  const bool hOK = (h < HID);
  const int hb = hOK ? h : 0;
  const float bz = bias[hb], bf = bias[hb + 800], bo = bias[hb + 1600];

  // phase 1: activate once, cache affine coeffs, compose segment map
  float av[32], bv[32];
  float Aa = 1.0f, Bb = 0.0f;
#pragma unroll
  for (int q = 0; q < 32; ++q) {
    const int t = s * 32 + q;
    const uint32_t v = Ep[t * 98 + hl];
    const float zv = fast_tanh(b2f(v & 0xffffu) + bz);
    const float fv = fast_sigmoid(b2f(v >> 16) + bf);
    av[q] = 1.0f - fv;
    bv[q] = fv * zv;
    Aa *= av[q];
    Bb = fmaf(av[q], Bb, bv[q]);
  }
  SA[s][hl] = Aa;
  SB[s][hl] = Bb;
  __syncthreads();
  // phase 2: serial combine over 4 segments, one thread per chain
  if (tid < 64) {
    const int h2 = ntile * 64 + tid;
    const bool ok2 = (h2 < HID);
    float c = (first || !ok2) ? 0.0f : carry[b * HID + h2];
#pragma unroll
    for (int ss = 0; ss < 4; ++ss) {
      SC[ss][tid] = c;
      c = fmaf(SA[ss][tid], c, SB[ss][tid]);
    }
    if (ok2) {
      carry[b * HID + h2] = c;
      if (last) outC[b * 2400 + outOff + h2] = c;
    }
  }
  __syncthreads();
  // phase 3: fma rescan from registers; h = sigmoid(o'+bo) * c (fp32 c)
  float c = SC[s][hl];
#pragma unroll
  for (int q = 0; q < 32; ++q) {
    const int t = s * 32 + q;
    c = fmaf(av[q], c, bv[q]);  // a*c + b == f*z + (1-f)*c
    const float o = fast_sigmoid((float)S[t * 196 + 128 + hl] + bo);
    Hout[(size_t)(b * 128 + t) * LDH + h] =
        hOK ? (bf16_t)(o * c) : (bf16_t)0.0f;  // zero K-pad cols [800,832)
  }
}

// ---- role body: zf-only GEMM (128 cols) + scan; carry/out only ----
__device__ __forceinline__ void scan_c_body(
    const bf16_t* __restrict__ A, const bf16_t* __restrict__ Wzf,
    const float* __restrict__ bias, float* __restrict__ carry,
    float* __restrict__ outC, int K, int outOff, int first, int last, int b,
    int ntile, bf16_t* S, float (*SA)[64], float (*SB)[64]) {
  gemm_tile_to_lds<4, 140>(A, Wzf, S, K, b * 128, ntile * 128);

  const uint32_t* Ep = (const uint32_t*)S;  // dword idx t*70+hl = (z,f)
  const int tid = threadIdx.x;
  const int hl = tid & 63, s = tid >> 6;
  const int h = ntile * 64 + hl;
  const int hb = (h < HID) ? h : 0;
  const float bz = bias[hb], bf = bias[hb + 800];

  float Aa = 1.0f, Bb = 0.0f;
#pragma unroll
  for (int q = 0; q < 32; ++q) {
    const int t = s * 32 + q;
    const uint32_t v = Ep[t * 70 + hl];
    const float zv = fast_tanh(b2f(v & 0xffffu) + bz);
    const float fv = fast_sigmoid(b2f(v >> 16) + bf);
    const float a = 1.0f - fv;
    Aa *= a;
    Bb = fmaf(a, Bb, fv * zv);
  }
  SA[s][hl] = Aa;
  SB[s][hl] = Bb;
  __syncthreads();
  if (tid < 64) {
    const int h2 = ntile * 64 + tid;
    const bool ok2 = (h2 < HID);
    float c = (first || !ok2) ? 0.0f : carry[b * HID + h2];
#pragma unroll
    for (int ss = 0; ss < 4; ++ss) c = fmaf(SA[ss][tid], c, SB[ss][tid]);
    if (ok2) {
      carry[b * HID + h2] = c;
      if (last) outC[b * 2400 + outOff + h2] = c;
    }
  }
}

__device__ __forceinline__ void block_tile(int& b, int& ntile) {
  const int nT = 13;
  const int L = blockIdx.y * nT + blockIdx.x;
  const int xcd = L & 7, j = L >> 3;
  b = xcd * 8 + j / nT;
  ntile = j % nT;
}

// ---- multi-role dispatch: blockIdx.z selects an independent role ----
struct Role {
  const bf16_t* A;
  const bf16_t* W;
  const float* bias;
  bf16_t* Hout;    // type 1 only
  float* carry;
  int K;
  int outOff;
  int type;        // 1 = zfo-GEMM + scan + h; 2 = zf-only + scan
  int first;
  int last;
};

__global__ __launch_bounds__(256, 3) void gemm_scan_multi(
    Role r0, Role r1, Role r2, float* __restrict__ outC) {
  __shared__ __align__(16) bf16_t S[25088];
  __shared__ float SA[4][64], SB[4][64], SC[4][64];
  int b, ntile;
  block_tile(b, ntile);
  const Role r = blockIdx.z == 0 ? r0 : (blockIdx.z == 1 ? r1 : r2);
  if (r.type == 1)
    scan_h_body(r.A, r.W, r.bias, r.Hout, r.carry, outC, r.K, r.outOff,
                r.first, r.last, b, ntile, S, SA, SB, SC);
  else
    scan_c_body(r.A, r.W, r.bias, r.carry, outC, r.K, r.outOff, r.first,
                r.last, b, ntile, S, SA, SB);
}

extern "C" void kernel_launch(void* const* d_in, const int* in_sizes, int n_in,
                              void* d_out, int out_size, void* d_ws, size_t ws_size,
                              hipStream_t stream) {
  const float* sent = (const float*)d_in[0];
  // d_in[1] = lengths: unused by the reference
  const float* W0 = (const float*)d_in[2];
  const float* b0 = (const float*)d_in[3];
  const float* W1 = (const float*)d_in[4];
  const float* b1 = (const float*)d_in[5];
  const float* W2 = (const float*)d_in[6];
  const float* b2 = (const float*)d_in[7];
  float* out = (float*)d_out;

  char* ws = (char*)d_ws;
  size_t off = 0;
  auto alloc = [&](size_t bytes) {
    void* p = ws + off;
    off += (bytes + 255) & ~(size_t)255;
    return p;
  };
  bf16_t* Wm0 = (bf16_t*)alloc((size_t)2496 * 320 * 2);   // 1.6 MB
  bf16_t* Wm1 = (bf16_t*)alloc((size_t)2496 * 832 * 2);   // 4.2 MB
  bf16_t* Wzf2 = (bf16_t*)alloc((size_t)1664 * 832 * 2);  // 2.8 MB
  bf16_t* A0 = (bf16_t*)alloc((size_t)32768 * 320 * 2);   // 21.0 MB
  bf16_t* H0buf[2], *H1buf[2];
  H0buf[0] = (bf16_t*)alloc((size_t)MC * LDH * 2);        // 13.6 MB each
  H0buf[1] = (bf16_t*)alloc((size_t)MC * LDH * 2);
  H1buf[0] = (bf16_t*)alloc((size_t)MC * LDH * 2);
  H1buf[1] = (bf16_t*)alloc((size_t)MC * LDH * 2);
  float* car0 = (float*)alloc((size_t)BATCH * HID * 4);   // 205 KB
  float* car1 = (float*)alloc((size_t)BATCH * HID * 4);
  float* car2 = (float*)alloc((size_t)BATCH * HID * 4);
  if (off > ws_size) return;  // ws too small: fail verification, don't fault

  cast_reorder_a0<<<(32768 * 320 + 255) / 256, 256, 0, stream>>>(sent, A0);
  transpose_cast_w<<<dim3(78, 26, 3), 256, 0, stream>>>(W0, W1, W2, Wm0, Wm1,
                                                        Wzf2);

  auto mkL0 = [&](int c) -> Role {
    return Role{A0 + (size_t)c * MC * 320, Wm0, b0, H0buf[c & 1], car0,
                320, 0, 1, c == 0, c == NCHUNK - 1};
  };
  auto mkL1 = [&](int c) -> Role {
    return Role{H0buf[c & 1], Wm1, b1, H1buf[c & 1], car1,
                832, 800, 1, c == 0, c == NCHUNK - 1};
  };
  auto mkL2 = [&](int c) -> Role {
    return Role{H1buf[c & 1], Wzf2, b2, nullptr, car2,
                832, 1600, 2, c == 0, c == NCHUNK - 1};
  };

  // D0: L0(0)
  {
    Role a = mkL0(0);
    gemm_scan_multi<<<dim3(13, 64, 1), 256, 0, stream>>>(a, a, a, out);
  }
  // D1: L1(0) + L0(1)
  {
    Role a = mkL1(0), b_ = mkL0(1);
    gemm_scan_multi<<<dim3(13, 64, 2), 256, 0, stream>>>(a, b_, b_, out);
  }
  // D2, D3: L1(c) + L2(c-1) + L0(c+1) for c = 1, 2
  for (int c = 1; c <= 2; ++c) {
    Role a = mkL1(c), b_ = mkL2(c - 1), d = mkL0(c + 1);
    gemm_scan_multi<<<dim3(13, 64, 3), 256, 0, stream>>>(a, b_, d, out);
  }
  // D4: L1(3) + L2(2)
  {
    Role a = mkL1(3), b_ = mkL2(2);
    gemm_scan_multi<<<dim3(13, 64, 2), 256, 0, stream>>>(a, b_, b_, out);
  }
  // D5: L2(3)
  {
    Role a = mkL2(3);
    gemm_scan_multi<<<dim3(13, 64, 1), 256, 0, stream>>>(a, a, a, out);
  }
}

// Round 16
// 465.366 us; speedup vs baseline: 1.4414x; 1.4414x over previous
//
#include <hip/hip_runtime.h>
#include <hip/hip_bf16.h>
#include <cstdint>
#include <cstddef>

// QRNN encoder, 3 layers. T=512 B=64 E=300 H=800.
// Chunked (4 x 128 steps, b-major rows b*128+t per chunk) fused GEMM+scan
// kernels packed into a 3-role pipeline per dispatch:
//   D(c) = { L1(c), L2(c-1), L0(c+1) } with double-buffered H0/H1.
// Prep consolidated — P0 = {W transposes + A0 chunk-0 cast} in one
// dispatch; A0 chunk 1-3 casts ride as filler roles in D0's idle tail.
// R16 fix: cast_op destination now includes the chunk offset (R15 wrote
// all chunks onto chunk 0 -> absmax 0.96).
// Role bodies (identical to R13):
//   scan_h: 128x192 zfo-GEMM tile (z at 2hl, f at 2hl+1, o at 128+hl)
//     + in-LDS segment scan (affine coeffs in registers) + h=sigmoid(o')*c.
//   scan_c: zf-only 128x128 tile + scan, carry/out only.
// GEMM: BK=64, XOR-swizzled LDS staging for A and B (0 bank conflicts;
// A-direct-to-reg tried in R14 and regressed — DMA staging wins), XCD-aware
// block swizzle, async global_load_lds. Workspace ~85 MB.

typedef __bf16 bf16_t;
typedef __bf16 bf16x8 __attribute__((ext_vector_type(8)));
typedef float f32x4 __attribute__((ext_vector_type(4)));

#define T_C 128
#define NCHUNK 4
#define BATCH 64
#define EMB 300
#define HID 800
#define LDH 832                 // h buffer leading dim (K-pad for BK=64)
#define MC (T_C * BATCH)        // 8192 rows per chunk
#define CAST_OPS (MC * 320 / 8) // 327680 bf16x8 ops per chunk cast

__device__ __forceinline__ float fast_sigmoid(float x) {
  return 1.0f / (1.0f + __expf(-x));
}
__device__ __forceinline__ float fast_tanh(float x) {
  return 2.0f / (1.0f + __expf(-2.0f * x)) - 1.0f;
}
__device__ __forceinline__ float b2f(uint32_t u) {
  union { uint32_t i; float f; } x;
  x.i = u << 16;
  return x.f;
}

// ---- cast body: sent [rows t*64+b][300] fp32 -> A0 chunk cc, b-major:
// dst row (global) = cc*8192 + b*128 + t, cols 0..319 (zero K-pad). ----
__device__ __forceinline__ void cast_op(const float* __restrict__ X,
                                        bf16_t* __restrict__ Y, int cc,
                                        int id) {
  const int rr = id / 40, cb = id - rr * 40;  // row in chunk, col-block(8)
  const int b = rr >> 7, t = rr & 127;
  const float* src = X + (size_t)((cc * 128 + t) * 64 + b) * EMB + cb * 8;
  bf16x8 w;
  if (cb < 37) {
    const f32x4 v0 = *(const f32x4*)src;
    const f32x4 v1 = *(const f32x4*)(src + 4);
#pragma unroll
    for (int e = 0; e < 4; ++e) {
      w[e] = (bf16_t)v0[e];
      w[e + 4] = (bf16_t)v1[e];
    }
  } else {
#pragma unroll
    for (int e = 0; e < 8; ++e) {
      const int col = cb * 8 + e;
      w[e] = (bf16_t)((col < EMB) ? src[e] : 0.0f);
    }
  }
  *(bf16x8*)&Y[((size_t)cc * MC + rr) * 320 + cb * 8] = w;  // R16 fix
}

// ---- P0: weights -> transposed bf16 buffers (+ chunk-0 cast at z=3).
// Merged zfo (z=0,1): Wm[2496][Kpad]; row n: tile j=n/192, r=n%192;
//   r<128: h=64j+(r>>1), src=(r&1)*800+h; r>=128: h=64j+(r-128), src=1600+h.
// zf-only (z=2): Wzf[1664][Kpad]; row n: h=n>>1, src=(n&1)*800+h. ----
__global__ __launch_bounds__(256) void prep_all(
    const float* __restrict__ W0, const float* __restrict__ W1,
    const float* __restrict__ W2, bf16_t* __restrict__ M0,
    bf16_t* __restrict__ M1, bf16_t* __restrict__ Z2,
    const float* __restrict__ sent, bf16_t* __restrict__ A0) {
  const int z = blockIdx.z;
  if (z == 3) {  // A0 chunk-0 cast
    const int id = (blockIdx.y * gridDim.x + blockIdx.x) * 256 + threadIdx.x;
    if (id < CAST_OPS) cast_op(sent, A0, 0, id);
    return;
  }
  const float* W = z == 0 ? W0 : (z == 1 ? W1 : W2);
  bf16_t* Wt = z == 0 ? M0 : (z == 1 ? M1 : Z2);
  const int K = z == 0 ? 300 : 800;
  const int Kpad = z == 0 ? 320 : 832;
  const int Npad = (z < 2) ? 2496 : 1664;
  const int i = blockIdx.x, j = blockIdx.y;
  if (i * 32 >= Npad || j * 32 >= Kpad) return;
  __shared__ float tile[32][33];
  const int tx = threadIdx.x & 31, ty = threadIdx.x >> 5;
#pragma unroll
  for (int r = 0; r < 32; r += 8) {
    const int k = j * 32 + ty + r;
    const int n = i * 32 + tx;
    int h, src;
    if (z < 2) {
      const int jt = n / 192, rr = n - jt * 192;
      if (rr < 128) {
        h = jt * 64 + (rr >> 1);
        src = (rr & 1) * 800 + h;
      } else {
        h = jt * 64 + (rr - 128);
        src = 1600 + h;
      }
    } else {
      h = n >> 1;
      src = (n & 1) * 800 + h;
    }
    const bool valid = (k < K) && (h < 800);
    tile[ty + r][tx] = valid ? W[(size_t)k * 2400 + src] : 0.0f;
  }
  __syncthreads();
#pragma unroll
  for (int r = 0; r < 32; r += 8) {
    const int n = i * 32 + ty + r, k = j * 32 + tx;
    if (n < Npad && k < Kpad)
      Wt[(size_t)n * Kpad + k] = (bf16_t)tile[tx][ty + r];
  }
}

// ---- async 16B global->LDS (wave-uniform base + lane*16 layout) ----
__device__ __forceinline__ void stage16(const bf16_t* gp, bf16_t* lp) {
  __builtin_amdgcn_global_load_lds((__attribute__((address_space(1))) void*)gp,
                                   (__attribute__((address_space(3))) void*)lp,
                                   16, 0, 0);
}

// GEMM core: 128 x (32*NTF) tile of A@Wt^T into Et[128][ETS] (bf16).
// 2x2 waves; each wave = 64 rows x (16*NTF) cols. XOR-swizzled staging,
// conflict-free ds_read_b128 fragment reads. B rows staged in NTF passes.
template <int NTF, int ETS>
__device__ __forceinline__ void gemm_tile_to_lds(
    const bf16_t* __restrict__ A, const bf16_t* __restrict__ Bt,
    bf16_t* __restrict__ S, int K, int mBase, int nBase) {
  bf16_t* As = S;
  bf16_t* Bs = S + 8192;
  const int tid = threadIdx.x;
  const int wave = tid >> 6, lane = tid & 63;
  const int wm = wave >> 1, wn = wave & 1;
  const int srow = tid >> 3;
  const int scolSw = ((tid & 7) ^ (srow & 7)) * 8;
  const size_t aBase = (size_t)(mBase + srow) * K + scolSw;
  const size_t bBase = (size_t)(nBase + srow) * K + scolSw;
  const int ldsOff = tid * 8;

  f32x4 acc[4][NTF];
#pragma unroll
  for (int mt = 0; mt < 4; ++mt)
#pragma unroll
    for (int nt = 0; nt < NTF; ++nt) {
      f32x4 zz = {0.0f, 0.0f, 0.0f, 0.0f};
      acc[mt][nt] = zz;
    }

  const int fr = lane & 15, fq = lane >> 4;
  const int x0 = fr & 7;
  const int ckEl0 = (fq ^ x0) * 8;
  const int ckEl1 = ((4 + fq) ^ x0) * 8;

  for (int k0 = 0; k0 < K; k0 += 64) {
#pragma unroll
    for (int p = 0; p < 4; ++p)
      stage16(A + aBase + (size_t)(32 * p) * K + k0, &As[ldsOff + p * 2048]);
#pragma unroll
    for (int p = 0; p < NTF; ++p)
      stage16(Bt + bBase + (size_t)(32 * p) * K + k0, &Bs[ldsOff + p * 2048]);
    __syncthreads();
#pragma unroll
    for (int kh = 0; kh < 2; ++kh) {
      const int ck = kh ? ckEl1 : ckEl0;
      bf16x8 af[4], bfv[NTF];
#pragma unroll
      for (int mt = 0; mt < 4; ++mt)
        af[mt] = *(const bf16x8*)&As[(wm * 64 + mt * 16 + fr) * 64 + ck];
#pragma unroll
      for (int nt = 0; nt < NTF; ++nt)
        bfv[nt] = *(const bf16x8*)&Bs[(wn * (16 * NTF) + nt * 16 + fr) * 64 + ck];
#pragma unroll
      for (int mt = 0; mt < 4; ++mt)
#pragma unroll
        for (int nt = 0; nt < NTF; ++nt)
          acc[mt][nt] = __builtin_amdgcn_mfma_f32_16x16x32_bf16(
              af[mt], bfv[nt], acc[mt][nt], 0, 0, 0);
    }
    __syncthreads();
  }
  // C/D layout col=lane&15, row=(lane>>4)*4+r -> Et[row][col], stride ETS.
  bf16_t* Et = S;
#pragma unroll
  for (int mt = 0; mt < 4; ++mt)
#pragma unroll
    for (int nt = 0; nt < NTF; ++nt)
#pragma unroll
      for (int r = 0; r < 4; ++r)
        Et[(wm * 64 + mt * 16 + fq * 4 + r) * ETS + wn * (16 * NTF) + nt * 16 +
           fr] = (bf16_t)acc[mt][nt][r];
  __syncthreads();
}

// ---- role body: zfo-GEMM (192 cols) + fused scan + h epilogue ----
__device__ __forceinline__ void scan_h_body(
    const bf16_t* __restrict__ A, const bf16_t* __restrict__ Wm,
    const float* __restrict__ bias, bf16_t* __restrict__ Hout,
    float* __restrict__ carry, float* __restrict__ outC, int K, int outOff,
    int first, int last, int b, int ntile, bf16_t* S, float (*SA)[64],
    float (*SB)[64], float (*SC)[64]) {
  gemm_tile_to_lds<6, 196>(A, Wm, S, K, b * 128, ntile * 192);

  const uint32_t* Ep = (const uint32_t*)S;  // dword idx t*98+hl = (z,f)
  const int tid = threadIdx.x;
  const int hl = tid & 63, s = tid >> 6;
  const int h = ntile * 64 + hl;
  const bool hOK = (h < HID);
  const int hb = hOK ? h : 0;
  const float bz = bias[hb], bf = bias[hb + 800], bo = bias[hb + 1600];

  // phase 1: activate once, cache affine coeffs, compose segment map
  float av[32], bv[32];
  float Aa = 1.0f, Bb = 0.0f;
#pragma unroll
  for (int q = 0; q < 32; ++q) {
    const int t = s * 32 + q;
    const uint32_t v = Ep[t * 98 + hl];
    const float zv = fast_tanh(b2f(v & 0xffffu) + bz);
    const float fv = fast_sigmoid(b2f(v >> 16) + bf);
    av[q] = 1.0f - fv;
    bv[q] = fv * zv;
    Aa *= av[q];
    Bb = fmaf(av[q], Bb, bv[q]);
  }
  SA[s][hl] = Aa;
  SB[s][hl] = Bb;
  __syncthreads();
  // phase 2: serial combine over 4 segments, one thread per chain
  if (tid < 64) {
    const int h2 = ntile * 64 + tid;
    const bool ok2 = (h2 < HID);
    float c = (first || !ok2) ? 0.0f : carry[b * HID + h2];
#pragma unroll
    for (int ss = 0; ss < 4; ++ss) {
      SC[ss][tid] = c;
      c = fmaf(SA[ss][tid], c, SB[ss][tid]);
    }
    if (ok2) {
      carry[b * HID + h2] = c;
      if (last) outC[b * 2400 + outOff + h2] = c;
    }
  }
  __syncthreads();
  // phase 3: fma rescan from registers; h = sigmoid(o'+bo) * c (fp32 c)
  float c = SC[s][hl];
#pragma unroll
  for (int q = 0; q < 32; ++q) {
    const int t = s * 32 + q;
    c = fmaf(av[q], c, bv[q]);  // a*c + b == f*z + (1-f)*c
    const float o = fast_sigmoid((float)S[t * 196 + 128 + hl] + bo);
    Hout[(size_t)(b * 128 + t) * LDH + h] =
        hOK ? (bf16_t)(o * c) : (bf16_t)0.0f;  // zero K-pad cols [800,832)
  }
}

// ---- role body: zf-only GEMM (128 cols) + scan; carry/out only ----
__device__ __forceinline__ void scan_c_body(
    const bf16_t* __restrict__ A, const bf16_t* __restrict__ Wzf,
    const float* __restrict__ bias, float* __restrict__ carry,
    float* __restrict__ outC, int K, int outOff, int first, int last, int b,
    int ntile, bf16_t* S, float (*SA)[64], float (*SB)[64]) {
  gemm_tile_to_lds<4, 140>(A, Wzf, S, K, b * 128, ntile * 128);

  const uint32_t* Ep = (const uint32_t*)S;  // dword idx t*70+hl = (z,f)
  const int tid = threadIdx.x;
  const int hl = tid & 63, s = tid >> 6;
  const int h = ntile * 64 + hl;
  const int hb = (h < HID) ? h : 0;
  const float bz = bias[hb], bf = bias[hb + 800];

  float Aa = 1.0f, Bb = 0.0f;
#pragma unroll
  for (int q = 0; q < 32; ++q) {
    const int t = s * 32 + q;
    const uint32_t v = Ep[t * 70 + hl];
    const float zv = fast_tanh(b2f(v & 0xffffu) + bz);
    const float fv = fast_sigmoid(b2f(v >> 16) + bf);
    const float a = 1.0f - fv;
    Aa *= a;
    Bb = fmaf(a, Bb, fv * zv);
  }
  SA[s][hl] = Aa;
  SB[s][hl] = Bb;
  __syncthreads();
  if (tid < 64) {
    const int h2 = ntile * 64 + tid;
    const bool ok2 = (h2 < HID);
    float c = (first || !ok2) ? 0.0f : carry[b * HID + h2];
#pragma unroll
    for (int ss = 0; ss < 4; ++ss) c = fmaf(SA[ss][tid], c, SB[ss][tid]);
    if (ok2) {
      carry[b * HID + h2] = c;
      if (last) outC[b * 2400 + outOff + h2] = c;
    }
  }
}

__device__ __forceinline__ void block_tile(int& b, int& ntile) {
  const int nT = 13;
  const int L = blockIdx.y * nT + blockIdx.x;
  const int xcd = L & 7, j = L >> 3;
  b = xcd * 8 + j / nT;
  ntile = j % nT;
}

// ---- multi-role dispatch: blockIdx.z selects an independent role ----
struct Role {
  const bf16_t* A;  // type 3: fp32 src (reinterpreted)
  const bf16_t* W;
  const float* bias;
  bf16_t* Hout;     // type 1: h out; type 3: bf16 A0 base dst
  float* carry;
  int K;
  int outOff;       // type 3: chunk index
  int type;         // 1 = zfo+scan+h; 2 = zf+scan; 3 = A0 chunk cast
  int first;
  int last;
};

__global__ __launch_bounds__(256, 3) void gemm_scan_multi(
    Role r0, Role r1, Role r2, Role r3, float* __restrict__ outC) {
  __shared__ __align__(16) bf16_t S[25088];
  __shared__ float SA[4][64], SB[4][64], SC[4][64];
  const Role r = blockIdx.z == 0
                     ? r0
                     : (blockIdx.z == 1 ? r1 : (blockIdx.z == 2 ? r2 : r3));
  if (r.type == 3) {
    int id = (blockIdx.y * gridDim.x + blockIdx.x) * 256 + threadIdx.x;
    const int stride = gridDim.x * gridDim.y * 256;  // 212992 at (13,64)
#pragma unroll
    for (int it = 0; it < 2; ++it, id += stride)
      if (id < CAST_OPS) cast_op((const float*)r.A, r.Hout, r.outOff, id);
    return;
  }
  int b, ntile;
  block_tile(b, ntile);
  if (r.type == 1)
    scan_h_body(r.A, r.W, r.bias, r.Hout, r.carry, outC, r.K, r.outOff,
                r.first, r.last, b, ntile, S, SA, SB, SC);
  else
    scan_c_body(r.A, r.W, r.bias, r.carry, outC, r.K, r.outOff, r.first,
                r.last, b, ntile, S, SA, SB);
}

extern "C" void kernel_launch(void* const* d_in, const int* in_sizes, int n_in,
                              void* d_out, int out_size, void* d_ws, size_t ws_size,
                              hipStream_t stream) {
  const float* sent = (const float*)d_in[0];
  // d_in[1] = lengths: unused by the reference
  const float* W0 = (const float*)d_in[2];
  const float* b0 = (const float*)d_in[3];
  const float* W1 = (const float*)d_in[4];
  const float* b1 = (const float*)d_in[5];
  const float* W2 = (const float*)d_in[6];
  const float* b2 = (const float*)d_in[7];
  float* out = (float*)d_out;

  char* ws = (char*)d_ws;
  size_t off = 0;
  auto alloc = [&](size_t bytes) {
    void* p = ws + off;
    off += (bytes + 255) & ~(size_t)255;
    return p;
  };
  bf16_t* Wm0 = (bf16_t*)alloc((size_t)2496 * 320 * 2);   // 1.6 MB
  bf16_t* Wm1 = (bf16_t*)alloc((size_t)2496 * 832 * 2);   // 4.2 MB
  bf16_t* Wzf2 = (bf16_t*)alloc((size_t)1664 * 832 * 2);  // 2.8 MB
  bf16_t* A0 = (bf16_t*)alloc((size_t)32768 * 320 * 2);   // 21.0 MB
  bf16_t* H0buf[2], *H1buf[2];
  H0buf[0] = (bf16_t*)alloc((size_t)MC * LDH * 2);        // 13.6 MB each
  H0buf[1] = (bf16_t*)alloc((size_t)MC * LDH * 2);
  H1buf[0] = (bf16_t*)alloc((size_t)MC * LDH * 2);
  H1buf[1] = (bf16_t*)alloc((size_t)MC * LDH * 2);
  float* car0 = (float*)alloc((size_t)BATCH * HID * 4);   // 205 KB
  float* car1 = (float*)alloc((size_t)BATCH * HID * 4);
  float* car2 = (float*)alloc((size_t)BATCH * HID * 4);
  if (off > ws_size) return;  // ws too small: fail verification, don't fault

  // P0: weight transposes (z=0..2) + A0 chunk-0 cast (z=3)
  prep_all<<<dim3(78, 26, 4), 256, 0, stream>>>(W0, W1, W2, Wm0, Wm1, Wzf2,
                                                sent, A0);

  auto mkL0 = [&](int c) -> Role {
    return Role{A0 + (size_t)c * MC * 320, Wm0, b0, H0buf[c & 1], car0,
                320, 0, 1, c == 0, c == NCHUNK - 1};
  };
  auto mkL1 = [&](int c) -> Role {
    return Role{H0buf[c & 1], Wm1, b1, H1buf[c & 1], car1,
                832, 800, 1, c == 0, c == NCHUNK - 1};
  };
  auto mkL2 = [&](int c) -> Role {
    return Role{H1buf[c & 1], Wzf2, b2, nullptr, car2,
                832, 1600, 2, c == 0, c == NCHUNK - 1};
  };
  auto mkCast = [&](int c) -> Role {
    return Role{(const bf16_t*)sent, nullptr, nullptr, A0, nullptr,
                0, c, 3, 0, 0};
  };

  // D0: L0(0) + cast chunks 1..3 (fill L0's idle tail with BW work)
  {
    Role a = mkL0(0), c1 = mkCast(1), c2 = mkCast(2), c3 = mkCast(3);
    gemm_scan_multi<<<dim3(13, 64, 4), 256, 0, stream>>>(a, c1, c2, c3, out);
  }
  // D1: L1(0) + L0(1)
  {
    Role a = mkL1(0), b_ = mkL0(1);
    gemm_scan_multi<<<dim3(13, 64, 2), 256, 0, stream>>>(a, b_, b_, b_, out);
  }
  // D2, D3: L1(c) + L2(c-1) + L0(c+1) for c = 1, 2
  for (int c = 1; c <= 2; ++c) {
    Role a = mkL1(c), b_ = mkL2(c - 1), d = mkL0(c + 1);
    gemm_scan_multi<<<dim3(13, 64, 3), 256, 0, stream>>>(a, b_, d, d, out);
  }
  // D4: L1(3) + L2(2)
  {
    Role a = mkL1(3), b_ = mkL2(2);
    gemm_scan_multi<<<dim3(13, 64, 2), 256, 0, stream>>>(a, b_, b_, b_, out);
  }
  // D5: L2(3)
  {
    Role a = mkL2(3);
    gemm_scan_multi<<<dim3(13, 64, 1), 256, 0, stream>>>(a, a, a, a, out);
  }
}

// Round 17
// 461.673 us; speedup vs baseline: 1.4529x; 1.0080x over previous
//
#include <hip/hip_runtime.h>
#include <hip/hip_bf16.h>
#include <cstdint>
#include <cstddef>

// QRNN encoder, 3 layers. T=512 B=64 E=300 H=800.
// Chunked (4 x 128 steps, b-major rows b*128+t per chunk) fused GEMM+scan
// kernels packed into a 3-role pipeline per dispatch:
//   D(c) = { L1(c), L2(c-1), L0(c+1) } with double-buffered H0/H1.
// P0 = {W transposes + A0 chunk-0 cast}; A0 chunk 1-3 casts ride in D0's
// idle tail. R17: (a) bias folded into GEMM via constant-1 K-pad column
// (A col K = 1.0, W row K = bias) — scan bodies drop all bias loads/adds;
// (b) dedicated 4-blocks/CU kernel for the final lone L2 dispatch (38 KB
// LDS vs 53 KB) — removes its block-wave tail.
// Role bodies:
//   scan_h: 128x192 zfo-GEMM tile (z at 2hl, f at 2hl+1, o at 128+hl)
//     + in-LDS segment scan (affine coeffs in registers) + h=sigmoid(o')*c.
//   scan_c: zf-only 128x128 tile + scan, carry/out only.
// GEMM: BK=64, XOR-swizzled LDS staging (0 bank conflicts; A-direct-to-reg
// regressed in R14 — DMA staging wins), XCD-aware block swizzle, async
// global_load_lds. Workspace ~85 MB.

typedef __bf16 bf16_t;
typedef __bf16 bf16x8 __attribute__((ext_vector_type(8)));
typedef float f32x4 __attribute__((ext_vector_type(4)));

#define T_C 128
#define NCHUNK 4
#define BATCH 64
#define EMB 300
#define HID 800
#define LDH 832                 // h buffer leading dim (K-pad for BK=64)
#define MC (T_C * BATCH)        // 8192 rows per chunk
#define CAST_OPS (MC * 320 / 8) // 327680 bf16x8 ops per chunk cast

__device__ __forceinline__ float fast_sigmoid(float x) {
  return 1.0f / (1.0f + __expf(-x));
}
__device__ __forceinline__ float fast_tanh(float x) {
  return 2.0f / (1.0f + __expf(-2.0f * x)) - 1.0f;
}
__device__ __forceinline__ float b2f(uint32_t u) {
  union { uint32_t i; float f; } x;
  x.i = u << 16;
  return x.f;
}

// ---- cast body: sent [rows t*64+b][300] fp32 -> A0 chunk cc, b-major:
// dst row (global) = cc*8192 + b*128 + t; col 300 = 1.0 (bias column),
// cols 301..319 = 0. ----
__device__ __forceinline__ void cast_op(const float* __restrict__ X,
                                        bf16_t* __restrict__ Y, int cc,
                                        int id) {
  const int rr = id / 40, cb = id - rr * 40;  // row in chunk, col-block(8)
  const int b = rr >> 7, t = rr & 127;
  const float* src = X + (size_t)((cc * 128 + t) * 64 + b) * EMB + cb * 8;
  bf16x8 w;
  if (cb < 37) {
    const f32x4 v0 = *(const f32x4*)src;
    const f32x4 v1 = *(const f32x4*)(src + 4);
#pragma unroll
    for (int e = 0; e < 4; ++e) {
      w[e] = (bf16_t)v0[e];
      w[e + 4] = (bf16_t)v1[e];
    }
  } else {
#pragma unroll
    for (int e = 0; e < 8; ++e) {
      const int col = cb * 8 + e;
      float v = (col < EMB) ? src[e] : (col == EMB ? 1.0f : 0.0f);
      w[e] = (bf16_t)v;
    }
  }
  *(bf16x8*)&Y[((size_t)cc * MC + rr) * 320 + cb * 8] = w;
}

// ---- P0: weights -> transposed bf16 buffers (+ chunk-0 cast at z=3).
// Bias folded in at k == K (multiplies the constant-1 A column).
// Merged zfo (z=0,1): Wm[2496][Kpad]; row n: tile j=n/192, r=n%192;
//   r<128: h=64j+(r>>1), src=(r&1)*800+h; r>=128: h=64j+(r-128), src=1600+h.
// zf-only (z=2): Wzf[1664][Kpad]; row n: h=n>>1, src=(n&1)*800+h. ----
__global__ __launch_bounds__(256) void prep_all(
    const float* __restrict__ W0, const float* __restrict__ W1,
    const float* __restrict__ W2, const float* __restrict__ B0,
    const float* __restrict__ B1, const float* __restrict__ B2,
    bf16_t* __restrict__ M0, bf16_t* __restrict__ M1, bf16_t* __restrict__ Z2,
    const float* __restrict__ sent, bf16_t* __restrict__ A0) {
  const int z = blockIdx.z;
  if (z == 3) {  // A0 chunk-0 cast
    const int id = (blockIdx.y * gridDim.x + blockIdx.x) * 256 + threadIdx.x;
    if (id < CAST_OPS) cast_op(sent, A0, 0, id);
    return;
  }
  const float* W = z == 0 ? W0 : (z == 1 ? W1 : W2);
  const float* Bv = z == 0 ? B0 : (z == 1 ? B1 : B2);
  bf16_t* Wt = z == 0 ? M0 : (z == 1 ? M1 : Z2);
  const int K = z == 0 ? 300 : 800;
  const int Kpad = z == 0 ? 320 : 832;
  const int Npad = (z < 2) ? 2496 : 1664;
  const int i = blockIdx.x, j = blockIdx.y;
  if (i * 32 >= Npad || j * 32 >= Kpad) return;
  __shared__ float tile[32][33];
  const int tx = threadIdx.x & 31, ty = threadIdx.x >> 5;
#pragma unroll
  for (int r = 0; r < 32; r += 8) {
    const int k = j * 32 + ty + r;
    const int n = i * 32 + tx;
    int h, src;
    if (z < 2) {
      const int jt = n / 192, rr = n - jt * 192;
      if (rr < 128) {
        h = jt * 64 + (rr >> 1);
        src = (rr & 1) * 800 + h;
      } else {
        h = jt * 64 + (rr - 128);
        src = 1600 + h;
      }
    } else {
      h = n >> 1;
      src = (n & 1) * 800 + h;
    }
    float v = 0.0f;
    if (h < 800) {
      if (k < K) v = W[(size_t)k * 2400 + src];
      else if (k == K) v = Bv[src];  // bias row (A pad col is 1.0)
    }
    tile[ty + r][tx] = v;
  }
  __syncthreads();
#pragma unroll
  for (int r = 0; r < 32; r += 8) {
    const int n = i * 32 + ty + r, k = j * 32 + tx;
    if (n < Npad && k < Kpad)
      Wt[(size_t)n * Kpad + k] = (bf16_t)tile[tx][ty + r];
  }
}

// ---- async 16B global->LDS (wave-uniform base + lane*16 layout) ----
__device__ __forceinline__ void stage16(const bf16_t* gp, bf16_t* lp) {
  __builtin_amdgcn_global_load_lds((__attribute__((address_space(1))) void*)gp,
                                   (__attribute__((address_space(3))) void*)lp,
                                   16, 0, 0);
}

// GEMM core: 128 x (32*NTF) tile of A@Wt^T into Et[128][ETS] (bf16).
// 2x2 waves; each wave = 64 rows x (16*NTF) cols. XOR-swizzled staging,
// conflict-free ds_read_b128 fragment reads. B rows staged in NTF passes.
template <int NTF, int ETS>
__device__ __forceinline__ void gemm_tile_to_lds(
    const bf16_t* __restrict__ A, const bf16_t* __restrict__ Bt,
    bf16_t* __restrict__ S, int K, int mBase, int nBase) {
  bf16_t* As = S;
  bf16_t* Bs = S + 8192;
  const int tid = threadIdx.x;
  const int wave = tid >> 6, lane = tid & 63;
  const int wm = wave >> 1, wn = wave & 1;
  const int srow = tid >> 3;
  const int scolSw = ((tid & 7) ^ (srow & 7)) * 8;
  const size_t aBase = (size_t)(mBase + srow) * K + scolSw;
  const size_t bBase = (size_t)(nBase + srow) * K + scolSw;
  const int ldsOff = tid * 8;

  f32x4 acc[4][NTF];
#pragma unroll
  for (int mt = 0; mt < 4; ++mt)
#pragma unroll
    for (int nt = 0; nt < NTF; ++nt) {
      f32x4 zz = {0.0f, 0.0f, 0.0f, 0.0f};
      acc[mt][nt] = zz;
    }

  const int fr = lane & 15, fq = lane >> 4;
  const int x0 = fr & 7;
  const int ckEl0 = (fq ^ x0) * 8;
  const int ckEl1 = ((4 + fq) ^ x0) * 8;

  for (int k0 = 0; k0 < K; k0 += 64) {
#pragma unroll
    for (int p = 0; p < 4; ++p)
      stage16(A + aBase + (size_t)(32 * p) * K + k0, &As[ldsOff + p * 2048]);
#pragma unroll
    for (int p = 0; p < NTF; ++p)
      stage16(Bt + bBase + (size_t)(32 * p) * K + k0, &Bs[ldsOff + p * 2048]);
    __syncthreads();
#pragma unroll
    for (int kh = 0; kh < 2; ++kh) {
      const int ck = kh ? ckEl1 : ckEl0;
      bf16x8 af[4], bfv[NTF];
#pragma unroll
      for (int mt = 0; mt < 4; ++mt)
        af[mt] = *(const bf16x8*)&As[(wm * 64 + mt * 16 + fr) * 64 + ck];
#pragma unroll
      for (int nt = 0; nt < NTF; ++nt)
        bfv[nt] = *(const bf16x8*)&Bs[(wn * (16 * NTF) + nt * 16 + fr) * 64 + ck];
#pragma unroll
      for (int mt = 0; mt < 4; ++mt)
#pragma unroll
        for (int nt = 0; nt < NTF; ++nt)
          acc[mt][nt] = __builtin_amdgcn_mfma_f32_16x16x32_bf16(
              af[mt], bfv[nt], acc[mt][nt], 0, 0, 0);
    }
    __syncthreads();
  }
  // C/D layout col=lane&15, row=(lane>>4)*4+r -> Et[row][col], stride ETS.
  bf16_t* Et = S;
#pragma unroll
  for (int mt = 0; mt < 4; ++mt)
#pragma unroll
    for (int nt = 0; nt < NTF; ++nt)
#pragma unroll
      for (int r = 0; r < 4; ++r)
        Et[(wm * 64 + mt * 16 + fq * 4 + r) * ETS + wn * (16 * NTF) + nt * 16 +
           fr] = (bf16_t)acc[mt][nt][r];
  __syncthreads();
}

// ---- role body: zfo-GEMM (192 cols) + fused scan + h epilogue ----
// Gates arrive pre-biased (bias folded into GEMM).
__device__ __forceinline__ void scan_h_body(
    const bf16_t* __restrict__ A, const bf16_t* __restrict__ Wm,
    bf16_t* __restrict__ Hout, float* __restrict__ carry,
    float* __restrict__ outC, int K, int outOff, int first, int last, int b,
    int ntile, bf16_t* S, float (*SA)[64], float (*SB)[64], float (*SC)[64]) {
  gemm_tile_to_lds<6, 196>(A, Wm, S, K, b * 128, ntile * 192);

  const uint32_t* Ep = (const uint32_t*)S;  // dword idx t*98+hl = (z,f)
  const int tid = threadIdx.x;
  const int hl = tid & 63, s = tid >> 6;
  const int h = ntile * 64 + hl;
  const bool hOK = (h < HID);

  // phase 1: activate once, cache affine coeffs, compose segment map
  float av[32], bv[32];
  float Aa = 1.0f, Bb = 0.0f;
#pragma unroll
  for (int q = 0; q < 32; ++q) {
    const int t = s * 32 + q;
    const uint32_t v = Ep[t * 98 + hl];
    const float zv = fast_tanh(b2f(v & 0xffffu));
    const float fv = fast_sigmoid(b2f(v >> 16));
    av[q] = 1.0f - fv;
    bv[q] = fv * zv;
    Aa *= av[q];
    Bb = fmaf(av[q], Bb, bv[q]);
  }
  SA[s][hl] = Aa;
  SB[s][hl] = Bb;
  __syncthreads();
  // phase 2: serial combine over 4 segments, one thread per chain
  if (tid < 64) {
    const int h2 = ntile * 64 + tid;
    const bool ok2 = (h2 < HID);
    float c = (first || !ok2) ? 0.0f : carry[b * HID + h2];
#pragma unroll
    for (int ss = 0; ss < 4; ++ss) {
      SC[ss][tid] = c;
      c = fmaf(SA[ss][tid], c, SB[ss][tid]);
    }
    if (ok2) {
      carry[b * HID + h2] = c;
      if (last) outC[b * 2400 + outOff + h2] = c;
    }
  }
  __syncthreads();
  // phase 3: fma rescan from registers; h = sigmoid(o') * c (fp32 c).
  // Pad cols: h == 800 -> 1.0 (next layer's bias column), else 0.
  const bf16_t padv = (h == HID) ? (bf16_t)1.0f : (bf16_t)0.0f;
  float c = SC[s][hl];
#pragma unroll
  for (int q = 0; q < 32; ++q) {
    const int t = s * 32 + q;
    c = fmaf(av[q], c, bv[q]);  // a*c + b == f*z + (1-f)*c
    const float o = fast_sigmoid((float)S[t * 196 + 128 + hl]);
    Hout[(size_t)(b * 128 + t) * LDH + h] = hOK ? (bf16_t)(o * c) : padv;
  }
}

// ---- role body: zf-only GEMM (128 cols) + scan; carry/out only ----
__device__ __forceinline__ void scan_c_body(
    const bf16_t* __restrict__ A, const bf16_t* __restrict__ Wzf,
    float* __restrict__ carry, float* __restrict__ outC, int K, int outOff,
    int first, int last, int b, int ntile, bf16_t* S, float (*SA)[64],
    float (*SB)[64]) {
  gemm_tile_to_lds<4, 140>(A, Wzf, S, K, b * 128, ntile * 128);

  const uint32_t* Ep = (const uint32_t*)S;  // dword idx t*70+hl = (z,f)
  const int tid = threadIdx.x;
  const int hl = tid & 63, s = tid >> 6;

  float Aa = 1.0f, Bb = 0.0f;
#pragma unroll
  for (int q = 0; q < 32; ++q) {
    const int t = s * 32 + q;
    const uint32_t v = Ep[t * 70 + hl];
    const float zv = fast_tanh(b2f(v & 0xffffu));
    const float fv = fast_sigmoid(b2f(v >> 16));
    const float a = 1.0f - fv;
    Aa *= a;
    Bb = fmaf(a, Bb, fv * zv);
  }
  SA[s][hl] = Aa;
  SB[s][hl] = Bb;
  __syncthreads();
  if (tid < 64) {
    const int h2 = ntile * 64 + tid;
    const bool ok2 = (h2 < HID);
    float c = (first || !ok2) ? 0.0f : carry[b * HID + h2];
#pragma unroll
    for (int ss = 0; ss < 4; ++ss) c = fmaf(SA[ss][tid], c, SB[ss][tid]);
    if (ok2) {
      carry[b * HID + h2] = c;
      if (last) outC[b * 2400 + outOff + h2] = c;
    }
  }
}

__device__ __forceinline__ void block_tile(int& b, int& ntile) {
  const int nT = 13;
  const int L = blockIdx.y * nT + blockIdx.x;
  const int xcd = L & 7, j = L >> 3;
  b = xcd * 8 + j / nT;
  ntile = j % nT;
}

// ---- multi-role dispatch: blockIdx.z selects an independent role ----
struct Role {
  const bf16_t* A;  // type 3: fp32 src (reinterpreted)
  const bf16_t* W;
  bf16_t* Hout;     // type 1: h out; type 3: bf16 A0 base dst
  float* carry;
  int K;
  int outOff;       // type 3: chunk index
  int type;         // 1 = zfo+scan+h; 2 = zf+scan; 3 = A0 chunk cast
  int first;
  int last;
};

__global__ __launch_bounds__(256, 3) void gemm_scan_multi(
    Role r0, Role r1, Role r2, Role r3, float* __restrict__ outC) {
  __shared__ __align__(16) bf16_t S[25088];
  __shared__ float SA[4][64], SB[4][64], SC[4][64];
  const Role r = blockIdx.z == 0
                     ? r0
                     : (blockIdx.z == 1 ? r1 : (blockIdx.z == 2 ? r2 : r3));
  if (r.type == 3) {
    int id = (blockIdx.y * gridDim.x + blockIdx.x) * 256 + threadIdx.x;
    const int stride = gridDim.x * gridDim.y * 256;  // 212992 at (13,64)
#pragma unroll
    for (int it = 0; it < 2; ++it, id += stride)
      if (id < CAST_OPS) cast_op((const float*)r.A, r.Hout, r.outOff, id);
    return;
  }
  int b, ntile;
  block_tile(b, ntile);
  if (r.type == 1)
    scan_h_body(r.A, r.W, r.Hout, r.carry, outC, r.K, r.outOff, r.first,
                r.last, b, ntile, S, SA, SB, SC);
  else
    scan_c_body(r.A, r.W, r.carry, outC, r.K, r.outOff, r.first, r.last, b,
                ntile, S, SA, SB);
}

// Dedicated final-L2 kernel: 38 KB LDS -> 4 blocks/CU, no block-wave tail.
__global__ __launch_bounds__(256, 4) void gemm_scan_c4(
    const bf16_t* __restrict__ A, const bf16_t* __restrict__ Wzf,
    float* __restrict__ carry, float* __restrict__ outC, int K, int outOff,
    int first, int last) {
  __shared__ __align__(16) bf16_t S[17920];
  __shared__ float SA[4][64], SB[4][64];
  int b, ntile;
  block_tile(b, ntile);
  scan_c_body(A, Wzf, carry, outC, K, outOff, first, last, b, ntile, S, SA,
              SB);
}

extern "C" void kernel_launch(void* const* d_in, const int* in_sizes, int n_in,
                              void* d_out, int out_size, void* d_ws, size_t ws_size,
                              hipStream_t stream) {
  const float* sent = (const float*)d_in[0];
  // d_in[1] = lengths: unused by the reference
  const float* W0 = (const float*)d_in[2];
  const float* b0 = (const float*)d_in[3];
  const float* W1 = (const float*)d_in[4];
  const float* b1 = (const float*)d_in[5];
  const float* W2 = (const float*)d_in[6];
  const float* b2 = (const float*)d_in[7];
  float* out = (float*)d_out;

  char* ws = (char*)d_ws;
  size_t off = 0;
  auto alloc = [&](size_t bytes) {
    void* p = ws + off;
    off += (bytes + 255) & ~(size_t)255;
    return p;
  };
  bf16_t* Wm0 = (bf16_t*)alloc((size_t)2496 * 320 * 2);   // 1.6 MB
  bf16_t* Wm1 = (bf16_t*)alloc((size_t)2496 * 832 * 2);   // 4.2 MB
  bf16_t* Wzf2 = (bf16_t*)alloc((size_t)1664 * 832 * 2);  // 2.8 MB
  bf16_t* A0 = (bf16_t*)alloc((size_t)32768 * 320 * 2);   // 21.0 MB
  bf16_t* H0buf[2], *H1buf[2];
  H0buf[0] = (bf16_t*)alloc((size_t)MC * LDH * 2);        // 13.6 MB each
  H0buf[1] = (bf16_t*)alloc((size_t)MC * LDH * 2);
  H1buf[0] = (bf16_t*)alloc((size_t)MC * LDH * 2);
  H1buf[1] = (bf16_t*)alloc((size_t)MC * LDH * 2);
  float* car0 = (float*)alloc((size_t)BATCH * HID * 4);   // 205 KB
  float* car1 = (float*)alloc((size_t)BATCH * HID * 4);
  float* car2 = (float*)alloc((size_t)BATCH * HID * 4);
  if (off > ws_size) return;  // ws too small: fail verification, don't fault

  // P0: weight transposes + bias rows (z=0..2) + A0 chunk-0 cast (z=3)
  prep_all<<<dim3(78, 26, 4), 256, 0, stream>>>(W0, W1, W2, b0, b1, b2, Wm0,
                                                Wm1, Wzf2, sent, A0);

  auto mkL0 = [&](int c) -> Role {
    return Role{A0 + (size_t)c * MC * 320, Wm0, H0buf[c & 1], car0,
                320, 0, 1, c == 0, c == NCHUNK - 1};
  };
  auto mkL1 = [&](int c) -> Role {
    return Role{H0buf[c & 1], Wm1, H1buf[c & 1], car1,
                832, 800, 1, c == 0, c == NCHUNK - 1};
  };
  auto mkL2 = [&](int c) -> Role {
    return Role{H1buf[c & 1], Wzf2, nullptr, car2,
                832, 1600, 2, c == 0, c == NCHUNK - 1};
  };
  auto mkCast = [&](int c) -> Role {
    return Role{(const bf16_t*)sent, nullptr, A0, nullptr, 0, c, 3, 0, 0};
  };

  // D0: L0(0) + cast chunks 1..3 (fill L0's idle tail with BW work)
  {
    Role a = mkL0(0), c1 = mkCast(1), c2 = mkCast(2), c3 = mkCast(3);
    gemm_scan_multi<<<dim3(13, 64, 4), 256, 0, stream>>>(a, c1, c2, c3, out);
  }
  // D1: L1(0) + L0(1)
  {
    Role a = mkL1(0), b_ = mkL0(1);
    gemm_scan_multi<<<dim3(13, 64, 2), 256, 0, stream>>>(a, b_, b_, b_, out);
  }
  // D2, D3: L1(c) + L2(c-1) + L0(c+1) for c = 1, 2
  for (int c = 1; c <= 2; ++c) {
    Role a = mkL1(c), b_ = mkL2(c - 1), d = mkL0(c + 1);
    gemm_scan_multi<<<dim3(13, 64, 3), 256, 0, stream>>>(a, b_, d, d, out);
  }
  // D4: L1(3) + L2(2)
  {
    Role a = mkL1(3), b_ = mkL2(2);
    gemm_scan_multi<<<dim3(13, 64, 2), 256, 0, stream>>>(a, b_, b_, b_, out);
  }
  // D5: final L2(3) on the 4-blocks/CU zf-only kernel (no tail)
  gemm_scan_c4<<<dim3(13, 64), 256, 0, stream>>>(H1buf[1], Wzf2, car2, out,
                                                 832, 1600, 0, 1);
}